// Round 17
// baseline (184.155 us; speedup 1.0000x reference)
//
#include <hip/hip_runtime.h>
#include <hip/hip_bf16.h>
#include <cstdint>

typedef short short8 __attribute__((ext_vector_type(8)));
typedef float f32x4 __attribute__((ext_vector_type(4)));
typedef unsigned uint4v __attribute__((ext_vector_type(4)));

#define MFMA16(a, b, c) __builtin_amdgcn_mfma_f32_16x16x32_bf16((a), (b), (c), 0, 0, 0)

__device__ __forceinline__ unsigned short f2b(float f) {
    __hip_bfloat16 h = __float2bfloat16(f);
    return __builtin_bit_cast(unsigned short, h);
}

__device__ __forceinline__ void gl_lds16(const void* g, void* l) {
    __builtin_amdgcn_global_load_lds((const __attribute__((address_space(1))) void*)g,
                                     (__attribute__((address_space(3))) void*)l, 16, 0, 0);
}

// (1/8) * log2(e): QK^T scores land in log2 domain -> bare v_exp_f32 softmax
#define QSC 0.18033688011112042f

// ---------------- RMSNorm: fp32 x -> bf16 xn ----------------
__global__ void rmsnorm_kernel(const float* __restrict__ x, const float* __restrict__ scale,
                               unsigned short* __restrict__ xn) {
    const int row = blockIdx.x;
    const int tid = threadIdx.x;
    const float4* xr = (const float4*)(x + (size_t)row * 1024);
    float4 vx = xr[tid];
    float ss = vx.x * vx.x + vx.y * vx.y + vx.z * vx.z + vx.w * vx.w;
#pragma unroll
    for (int m = 1; m < 64; m <<= 1) ss += __shfl_xor(ss, m);
    __shared__ float wsum[4];
    if ((tid & 63) == 0) wsum[tid >> 6] = ss;
    __syncthreads();
    float tot = wsum[0] + wsum[1] + wsum[2] + wsum[3];
    float rs = rsqrtf(tot * (1.0f / 1024.0f) + 1e-6f);
    const float4* sr = (const float4*)scale;
    float4 sv = sr[tid];
    ushort4 r;
    r.x = f2b(vx.x * sv.x * rs);
    r.y = f2b(vx.y * sv.y * rs);
    r.z = f2b(vx.z * sv.z * rs);
    r.w = f2b(vx.w * sv.w * rs);
    *(ushort4*)(xn + (size_t)row * 1024 + tid * 4) = r;
}

// ---------------- f32 -> bf16 convert ----------------
__global__ void f2b_kernel(const float* __restrict__ in, unsigned short* __restrict__ outp, int n4) {
    int i = blockIdx.x * 256 + threadIdx.x;
    if (i < n4) {
        float4 vv = ((const float4*)in)[i];
        ushort4 r;
        r.x = f2b(vv.x);
        r.y = f2b(vv.y);
        r.z = f2b(vv.z);
        r.w = f2b(vv.w);
        ((ushort4*)outp)[i] = r;
    }
}

// ---------------- GEMM C = A * B^T, m97 structure (kept for EPI 1 / out-proj) ----
constexpr int BM = 128, BN = 128, BK = 64, KDIM = 1024, NT = KDIM / BK;

template <int EPI>
__launch_bounds__(256, 4) __global__
    void gemm_bt(const unsigned short* __restrict__ A, const unsigned short* __restrict__ Bw,
                 unsigned short* __restrict__ qo, unsigned short* __restrict__ ko,
                 unsigned short* __restrict__ vo, const float* __restrict__ skip,
                 float* __restrict__ out, const float* __restrict__ theta) {
    __shared__ unsigned short As[BM * BK];
    __shared__ unsigned short Bs[BN * BK];
    const int tid = threadIdx.x;
    const int lane = tid & 63, w = tid >> 6;
    const int wr = w >> 1, wc = w & 1;
    const int lr = lane & 15, lg = lane >> 4;
    constexpr int NBX = (EPI == 0) ? 24 : 8;
    const int f = blockIdx.x;
    const int xcd = f & 7, wloc = f >> 3;
    const int g = xcd * (NBX * 8) + wloc;
    const int bx = g % NBX, by = g / NBX;
    const int m0 = by * BM;
    const int n0 = bx * BN;
    const int NCOL = (EPI == 0) ? 3072 : 1024;

    f32x4 acc[4][4] = {};

    auto stage = [&](int kt) {
        const int k0 = kt * BK;
#pragma unroll
        for (int i = 0; i < 4; ++i) {
            int seg = i * 256 + tid;
            int row = seg >> 3, c8 = (seg & 7) ^ (row & 7);
            gl_lds16(A + (size_t)(m0 + row) * KDIM + k0 + c8 * 8, &As[(i * 256 + w * 64) * 8]);
            gl_lds16(Bw + (size_t)(n0 + row) * KDIM + k0 + c8 * 8, &Bs[(i * 256 + w * 64) * 8]);
        }
    };

    for (int kt = 0; kt < NT; ++kt) {
        stage(kt);
        __syncthreads();
#pragma unroll
        for (int kkc = 0; kkc < 2; ++kkc) {
            short8 a[4], b[4];
            const int slot = ((kkc * 4 + lg) ^ (lr & 7)) * 8;
#pragma unroll
            for (int m = 0; m < 4; ++m)
                a[m] = *(const short8*)&As[(wr * 64 + m * 16 + lr) * BK + slot];
#pragma unroll
            for (int n = 0; n < 4; ++n)
                b[n] = *(const short8*)&Bs[(wc * 64 + n * 16 + lr) * BK + slot];
#pragma unroll
            for (int m = 0; m < 4; ++m)
#pragma unroll
                for (int n = 0; n < 4; ++n) acc[m][n] = MFMA16(a[m], b[n], acc[m][n]);
        }
        __syncthreads();
    }

    if (EPI == 0) {
        const int colb = n0 + wc * 64;
        const int c = colb >> 10, h = (colb >> 6) & 15;
#pragma unroll
        for (int m = 0; m < 4; ++m) {
            int grow0 = m0 + wr * 64 + m * 16 + lg * 4;
            int b = grow0 >> 10, s0 = grow0 & 1023;
            if (c == 2) {
#pragma unroll
                for (int n = 0; n < 4; ++n) {
                    int d = n * 16 + lr;
                    ushort4 r;
                    r.x = f2b(acc[m][n][0]);
                    r.y = f2b(acc[m][n][1]);
                    r.z = f2b(acc[m][n][2]);
                    r.w = f2b(acc[m][n][3]);
                    *(ushort4*)&vo[(((size_t)(b * 16 + h)) * 64 + d) * 1024 + s0] = r;
                }
            } else {
                unsigned short* dst = (c == 0) ? qo : ko;
                float sc = (c == 0) ? QSC : 1.0f;
#pragma unroll
                for (int j = 0; j < 4; ++j) {
                    int s = s0 + j;
                    float th = theta[((s * 16 + h) << 4) + lr];
                    float sn, cs;
                    __sincosf(th, &sn, &cs);
                    float x1 = acc[m][0][j], x2 = acc[m][1][j];
                    size_t rowb = (((size_t)(b * 16 + h)) * 1024 + s) * 64;
                    dst[rowb + lr]      = f2b((x1 * cs - x2 * sn) * sc);
                    dst[rowb + 16 + lr] = f2b((x2 * cs + x1 * sn) * sc);
                    dst[rowb + 32 + lr] = f2b(acc[m][2][j] * sc);
                    dst[rowb + 48 + lr] = f2b(acc[m][3][j] * sc);
                }
            }
        }
    } else {
#pragma unroll
        for (int m = 0; m < 4; ++m)
#pragma unroll
            for (int n = 0; n < 4; ++n) {
                int gcol = n0 + wc * 64 + n * 16 + lr;
#pragma unroll
                for (int j = 0; j < 4; ++j) {
                    int grow = m0 + wr * 64 + m * 16 + lg * 4 + j;
                    size_t idx = (size_t)grow * NCOL + gcol;
                    out[idx] = acc[m][n][j] + skip[idx];
                }
            }
    }
}

// ---------------- QKV GEMM: 256x256 8-phase pipelined (template-correct) -------------
// Phase = { vmcnt(counted) ; 12x ds_read_b128 into regs ; stage 1 half-tile ;
//           barrier ; setprio(1) 16 MFMA setprio(0) ; barrier }.
// ds_reads issued PRE-barrier so their latency overlaps the barrier wait and the
// other wave's MFMA block (the m201 lever). Cross-wave visibility ledger: half h
// staged at slot h-4; slot g reads halves <= g+1; slot g-1's vmcnt(2) (all but
// newest 1 half) + barrier guarantees them resident for ALL waves. Prologue
// vmcnt(4); tail (t15) vmcnt {2,0,0,0}. Loads never drain to 0 mid-loop.
__launch_bounds__(512, 2) __global__
    void gemm256_qkv(const unsigned short* __restrict__ A, const unsigned short* __restrict__ Bw,
                     unsigned short* __restrict__ qo, unsigned short* __restrict__ ko,
                     unsigned short* __restrict__ vo, const float* __restrict__ theta) {
    __shared__ unsigned short As[2][256 * 64];
    __shared__ unsigned short Bs[2][256 * 64];
    const int tid = threadIdx.x;           // 0..511
    const int lane = tid & 63, w = tid >> 6;
    const int wm = w >> 2, wn = w & 3;     // 2M x 4N
    const int lr = lane & 15, lg = lane >> 4;
    // XCD-bijective swizzle over 384 blocks (48 per XCD)
    const int f = blockIdx.x;
    const int xcd = f & 7, wloc = f >> 3;
    const int g = xcd * 48 + wloc;
    const int bx = g % 12, by = g / 12;
    const int m0 = by * 256, n0 = bx * 256;

    f32x4 acc[2][2][4][2] = {};  // [mh][nh][m][n]

#define STAGE_A(buf, kt, h)                                                            \
    {                                                                                  \
        _Pragma("unroll") for (int i = 0; i < 2; ++i) {                                \
            int seg = i * 512 + tid;                                                   \
            int row = seg >> 3, cs = (seg & 7) ^ (row & 7);                            \
            gl_lds16(A + (size_t)(m0 + (h)*128 + row) * 1024 + (kt)*64 + cs * 8,       \
                     &As[buf][(h)*8192 + (i * 512 + w * 64) * 8]);                     \
        }                                                                              \
    }
#define STAGE_B(buf, kt, h)                                                            \
    {                                                                                  \
        _Pragma("unroll") for (int i = 0; i < 2; ++i) {                                \
            int seg = i * 512 + tid;                                                   \
            int row = seg >> 3, cs = (seg & 7) ^ (row & 7);                            \
            gl_lds16(Bw + (size_t)(n0 + (h)*128 + row) * 1024 + (kt)*64 + cs * 8,      \
                     &Bs[buf][(h)*8192 + (i * 512 + w * 64) * 8]);                     \
        }                                                                              \
    }
#define VMW(N) asm volatile("s_waitcnt vmcnt(" #N ")" ::: "memory")
#define BARX()                              \
    {                                       \
        asm volatile("" ::: "memory");      \
        __builtin_amdgcn_s_barrier();       \
        asm volatile("" ::: "memory");      \
    }
#define PHASE(S, VMN, buf, mh, nh)                                                     \
    {                                                                                  \
        VMW(VMN);                                                                      \
        short8 afr[4][2], bfr[2][2];                                                   \
        _Pragma("unroll") for (int m = 0; m < 4; ++m)                                  \
            _Pragma("unroll") for (int kk = 0; kk < 2; ++kk) {                         \
                int r = (mh)*128 + wm * 64 + m * 16 + lr;                              \
                int slot = (kk * 4 + lg) ^ (r & 7);                                    \
                afr[m][kk] = *(const short8*)&As[buf][r * 64 + slot * 8];              \
            }                                                                          \
        _Pragma("unroll") for (int n = 0; n < 2; ++n)                                  \
            _Pragma("unroll") for (int kk = 0; kk < 2; ++kk) {                         \
                int c = (nh)*128 + wn * 32 + n * 16 + lr;                              \
                int slot = (kk * 4 + lg) ^ (c & 7);                                    \
                bfr[n][kk] = *(const short8*)&Bs[buf][c * 64 + slot * 8];              \
            }                                                                          \
        S;                                                                             \
        BARX();                                                                        \
        __builtin_amdgcn_s_setprio(1);                                                 \
        _Pragma("unroll") for (int kk = 0; kk < 2; ++kk)                               \
            _Pragma("unroll") for (int m = 0; m < 4; ++m)                              \
                _Pragma("unroll") for (int n = 0; n < 2; ++n)                          \
                    acc[mh][nh][m][n] = MFMA16(afr[m][kk], bfr[n][kk],                 \
                                               acc[mh][nh][m][n]);                     \
        __builtin_amdgcn_s_setprio(0);                                                 \
        BARX();                                                                        \
    }

    // Prologue: tile 0 -> buf0 in order Ah0, Bh0, Ah1, Bh1; drain halves 0,1
    STAGE_A(0, 0, 0);
    STAGE_B(0, 0, 0);
    STAGE_A(0, 0, 1);
    STAGE_B(0, 0, 1);
    VMW(4);
    BARX();

    for (int i = 0; i < 7; ++i) {
        const int tb = 2 * i + 1, tc = 2 * i + 2;
        // phases 0-3: compute tile 2i (buf0); stage tile 2i+1 -> buf1
        PHASE(STAGE_A(1, tb, 0), 2, 0, 0, 0);
        PHASE(STAGE_B(1, tb, 0), 2, 0, 1, 0);
        PHASE(STAGE_A(1, tb, 1), 2, 0, 0, 1);
        PHASE(STAGE_B(1, tb, 1), 2, 0, 1, 1);
        // phases 4-7: compute tile 2i+1 (buf1); stage tile 2i+2 -> buf0
        PHASE(STAGE_A(0, tc, 0), 2, 1, 0, 0);
        PHASE(STAGE_B(0, tc, 0), 2, 1, 1, 0);
        PHASE(STAGE_A(0, tc, 1), 2, 1, 0, 1);
        PHASE(STAGE_B(0, tc, 1), 2, 1, 1, 1);
    }
    // final iteration: tile 14 (buf0, staging t15) then tile 15 (buf1, no stage)
    PHASE(STAGE_A(1, 15, 0), 2, 0, 0, 0);
    PHASE(STAGE_B(1, 15, 0), 2, 0, 1, 0);
    PHASE(STAGE_A(1, 15, 1), 2, 0, 0, 1);
    PHASE(STAGE_B(1, 15, 1), 2, 0, 1, 1);
    PHASE(((void)0), 2, 1, 0, 0);
    PHASE(((void)0), 0, 1, 1, 0);
    PHASE(((void)0), 0, 1, 0, 1);
    PHASE(((void)0), 0, 1, 1, 1);

#undef PHASE
#undef BARX
#undef VMW
#undef STAGE_B
#undef STAGE_A

    // Epilogue: scatter q (RoPE+QSC), k (RoPE), v (transposed B,H,D,S)
#pragma unroll
    for (int nh = 0; nh < 2; ++nh) {
        const int X = n0 + nh * 128 + wn * 32;
        const int c = X >> 10, hh = (X >> 6) & 15;
        const bool lowh = (X & 63) == 0;
#pragma unroll
        for (int mh = 0; mh < 2; ++mh)
#pragma unroll
            for (int m = 0; m < 4; ++m) {
                int grow0 = m0 + mh * 128 + wm * 64 + m * 16 + lg * 4;
                int bb = grow0 >> 10, s0 = grow0 & 1023;
                if (c == 2) {
#pragma unroll
                    for (int n = 0; n < 2; ++n) {
                        int d = (X & 63) + n * 16 + lr;
                        ushort4 r4;
                        r4.x = f2b(acc[mh][nh][m][n][0]);
                        r4.y = f2b(acc[mh][nh][m][n][1]);
                        r4.z = f2b(acc[mh][nh][m][n][2]);
                        r4.w = f2b(acc[mh][nh][m][n][3]);
                        *(ushort4*)&vo[(((size_t)(bb * 16 + hh)) * 64 + d) * 1024 + s0] = r4;
                    }
                } else {
                    unsigned short* dst = (c == 0) ? qo : ko;
                    float sc = (c == 0) ? QSC : 1.0f;
                    if (lowh) {
#pragma unroll
                        for (int j = 0; j < 4; ++j) {
                            int s = s0 + j;
                            float th = theta[((s * 16 + hh) << 4) + lr];
                            float sn, cs2;
                            __sincosf(th, &sn, &cs2);
                            float x1 = acc[mh][nh][m][0][j], x2 = acc[mh][nh][m][1][j];
                            size_t rowb = (((size_t)(bb * 16 + hh)) * 1024 + s) * 64;
                            dst[rowb + lr]      = f2b((x1 * cs2 - x2 * sn) * sc);
                            dst[rowb + 16 + lr] = f2b((x2 * cs2 + x1 * sn) * sc);
                        }
                    } else {
#pragma unroll
                        for (int j = 0; j < 4; ++j) {
                            int s = s0 + j;
                            size_t rowb = (((size_t)(bb * 16 + hh)) * 1024 + s) * 64;
                            dst[rowb + 32 + lr] = f2b(acc[mh][nh][m][0][j] * sc);
                            dst[rowb + 48 + lr] = f2b(acc[mh][nh][m][1][j] * sc);
                        }
                    }
                }
            }
    }
}

// ---------------- Flash attention (causal), QBLK=256, 8 waves, swapped-operand ------
// (byte-identical to round-15 PASS)
__launch_bounds__(512, 4) __global__
    void attn_kernel(const unsigned short* __restrict__ q, const unsigned short* __restrict__ k,
                     const unsigned short* __restrict__ vt, unsigned short* __restrict__ o) {
    constexpr int S = 1024, D = 64;
    __shared__ unsigned short Ks[2][64 * 64];  // [t][d], chunk-swizzled
    __shared__ unsigned short Vs[2][64 * 64];  // [d][t], chunk-swizzled
    __shared__ float Lls[8][32];               // per-wave final-l redistribution
    const int tid = threadIdx.x, lane = tid & 63, w = tid >> 6;  // w = 0..7
    const int lr = lane & 15, lg = lane >> 4;
    const int f = blockIdx.x;  // 0..511
    constexpr int qmap4[4] = {3, 2, 0, 1};
    const int qb = qmap4[f >> 7];
    const int bh = (f & 7) * 16 + ((f >> 3) & 15);
    const int qs = qb * 256;
    const size_t base = (size_t)bh * (S * D);
    const int wrow0 = qs + w * 32;

    short8 qf[2][2];
#pragma unroll
    for (int m = 0; m < 2; ++m) {
        const unsigned short* qp = q + base + (size_t)(wrow0 + m * 16 + lr) * D;
        qf[m][0] = *(const short8*)(qp + lg * 8);
        qf[m][1] = *(const short8*)(qp + 32 + lg * 8);
    }

    f32x4 of[2][4] = {};  // O[q = wrow0 + m*16 + lg*4 + j][d = 16*n2 + lr]
    float mrun[2] = {-1e30f, -1e30f};
    float lrun[2] = {0.f, 0.f};  // per-lane partial (own t-subset); reduced at end

    const int nkt = 4 * qb + 4;

    // one 16B chunk per thread per tensor: 512 threads x 16B = one 64x64 bf16 tile
    const int srow = tid >> 3, sc8 = (tid & 7) ^ (srow & 7);
    auto stageK = [&](int buf, int kt) {
        gl_lds16(k + base + (size_t)(kt * 64 + srow) * D + sc8 * 8, &Ks[buf][w * 512]);
    };
    auto stageV = [&](int buf, int kt) {
        gl_lds16(vt + base + (size_t)srow * S + kt * 64 + sc8 * 8, &Vs[buf][w * 512]);
    };

    stageK(0, 0);
    stageV(0, 0);
    __syncthreads();

    for (int kt = 0; kt < nkt; ++kt) {
        const int b = kt & 1;
        if (kt + 1 < nkt) {
            stageK(b ^ 1, kt + 1);
            stageV(b ^ 1, kt + 1);
        }

        if (kt * 64 <= wrow0 + 31) {  // wave-uniform: this wave has unmasked rows
            // Swapped QK^T: sf[m][n][j] = S^T[t = kt*64+16n+lg*4+j][q = wrow0+m*16+lr]
            f32x4 sf[2][4] = {};
            __builtin_amdgcn_s_setprio(1);
#pragma unroll
            for (int n = 0; n < 4; ++n) {
                const int r = n * 16 + lr;
#pragma unroll
                for (int kkc = 0; kkc < 2; ++kkc) {
                    short8 kf = *(const short8*)&Ks[b][r * 64 + (((kkc * 4 + lg) ^ (lr & 7)) * 8)];
#pragma unroll
                    for (int m = 0; m < 2; ++m) sf[m][n] = MFMA16(kf, qf[m][kkc], sf[m][n]);
                }
            }
            __builtin_amdgcn_s_setprio(0);

            if (kt * 64 + 63 > wrow0) {  // tile overlaps diagonal for this wave
#pragma unroll
                for (int m = 0; m < 2; ++m)
#pragma unroll
                    for (int n = 0; n < 4; ++n)
#pragma unroll
                        for (int j = 0; j < 4; ++j) {
                            int t = kt * 64 + 16 * n + lg * 4 + j;
                            int qr = wrow0 + m * 16 + lr;
                            if (t > qr) sf[m][n][j] = -1e30f;
                        }
            }

#pragma unroll
            for (int m = 0; m < 2; ++m) {
                float mx = -1e30f;
#pragma unroll
                for (int n = 0; n < 4; ++n)
                    mx = fmaxf(mx, fmaxf(fmaxf(sf[m][n][0], sf[m][n][1]),
                                         fmaxf(sf[m][n][2], sf[m][n][3])));
                mx = fmaxf(mx, __shfl_xor(mx, 16));
                mx = fmaxf(mx, __shfl_xor(mx, 32));

                if (__any(mx > mrun[m] + 8.0f)) {
                    float newm = fmaxf(mrun[m], mx);
                    float sc = __builtin_amdgcn_exp2f(mrun[m] - newm);
                    mrun[m] = newm;
                    float psum = 0.f;
#pragma unroll
                    for (int n = 0; n < 4; ++n)
#pragma unroll
                        for (int j = 0; j < 4; ++j) {
                            float p = __builtin_amdgcn_exp2f(sf[m][n][j] - newm);
                            sf[m][n][j] = p;
                            psum += p;
                        }
                    lrun[m] = lrun[m] * sc + psum;
#pragma unroll
                    for (int n2 = 0; n2 < 4; ++n2) of[m][n2] *= sc;
                } else {
                    float mo = mrun[m];
                    float psum = 0.f;
#pragma unroll
                    for (int n = 0; n < 4; ++n)
#pragma unroll
                        for (int j = 0; j < 4; ++j) {
                            float p = __builtin_amdgcn_exp2f(sf[m][n][j] - mo);
                            sf[m][n][j] = p;
                            psum += p;
                        }
                    lrun[m] += psum;
                }
            }

            // P -> PV A-frags via permlane32/16_swap in-register transpose (no LDS).
            short8 pa[2][2];  // [m][kkc]
#pragma unroll
            for (int m = 0; m < 2; ++m) {
                unsigned Dk[4][2];
#pragma unroll
                for (int n = 0; n < 4; ++n)
#pragma unroll
                    for (int w2 = 0; w2 < 2; ++w2)
                        Dk[n][w2] = (unsigned)f2b(sf[m][n][2 * w2]) |
                                    ((unsigned)f2b(sf[m][n][2 * w2 + 1]) << 16);
#pragma unroll
                for (int n1 = 0; n1 < 2; ++n1) {
                    unsigned fr[4];
#pragma unroll
                    for (int w2 = 0; w2 < 2; ++w2) {
                        unsigned X0 = Dk[2 * n1][w2];      // r=0 (n0=0)
                        unsigned X1 = Dk[2 * n1 + 1][w2];  // r=1 (n0=1)
                        asm("v_permlane32_swap_b32 %0, %1" : "+v"(X0), "+v"(X1));
                        asm("v_permlane16_swap_b32 %0, %1" : "+v"(X0), "+v"(X1));
                        fr[w2] = X0;      // dd = w2
                        fr[2 + w2] = X1;  // dd = 2 + w2
                    }
                    uint4v t4 = {fr[0], fr[1], fr[2], fr[3]};
                    pa[m][n1] = __builtin_bit_cast(short8, t4);
                }
            }

            // PV: O[q][d] += P[q][t] * V[t][d]; V^T-frag read identical to K-frag
            __builtin_amdgcn_s_setprio(1);
#pragma unroll
            for (int kkc = 0; kkc < 2; ++kkc) {
#pragma unroll
                for (int n2 = 0; n2 < 4; ++n2) {
                    const int r = n2 * 16 + lr;
                    short8 bv = *(const short8*)&Vs[b][r * 64 + (((kkc * 4 + lg) ^ (lr & 7)) * 8)];
#pragma unroll
                    for (int m = 0; m < 2; ++m) of[m][n2] = MFMA16(pa[m][kkc], bv, of[m][n2]);
                }
            }
            __builtin_amdgcn_s_setprio(0);
        }

        __syncthreads();
    }

    // final l per q-row, redistributed through the per-wave L buffer
#pragma unroll
    for (int m = 0; m < 2; ++m) {
        float l = lrun[m];
        l += __shfl_xor(l, 16);
        l += __shfl_xor(l, 32);
        Lls[w][m * 16 + lr] = l;  // all lg write the same value
    }
    const int bb = bh >> 4, h = bh & 15;
#pragma unroll
    for (int m = 0; m < 2; ++m)
#pragma unroll
        for (int j = 0; j < 4; ++j) {
            float inv = 1.f / Lls[w][m * 16 + lg * 4 + j];
            int orow = wrow0 + m * 16 + lg * 4 + j;
            size_t ob = ((size_t)(bb * 1024 + orow)) * 1024 + h * 64;
#pragma unroll
            for (int n2 = 0; n2 < 4; ++n2)
                o[ob + n2 * 16 + lr] = f2b(of[m][n2][j] * inv);
        }
}

extern "C" void kernel_launch(void* const* d_in, const int* in_sizes, int n_in, void* d_out,
                              int out_size, void* d_ws, size_t ws_size, hipStream_t stream) {
    const float* x = (const float*)d_in[0];
    const float* scale = (const float*)d_in[1];
    const float* w_qkv = (const float*)d_in[2];
    const float* w_out = (const float*)d_in[3];
    const float* theta = (const float*)d_in[4];
    float* out = (float*)d_out;

    char* p = (char*)d_ws;
    unsigned short* xn = (unsigned short*)p;      p += (size_t)8192 * 1024 * 2;
    unsigned short* wqb = (unsigned short*)p;     p += (size_t)3072 * 1024 * 2;
    unsigned short* wob = (unsigned short*)p;     p += (size_t)1024 * 1024 * 2;
    unsigned short* qb_ = (unsigned short*)p;     p += (size_t)128 * 1024 * 64 * 2;
    unsigned short* kb_ = (unsigned short*)p;     p += (size_t)128 * 1024 * 64 * 2;
    unsigned short* vb_ = (unsigned short*)p;     p += (size_t)128 * 1024 * 64 * 2;  // V^T (B,H,D,S)
    unsigned short* ob_ = (unsigned short*)p;     p += (size_t)8192 * 1024 * 2;

    rmsnorm_kernel<<<8192, 256, 0, stream>>>(x, scale, xn);
    f2b_kernel<<<3072, 256, 0, stream>>>(w_qkv, wqb, 786432);
    f2b_kernel<<<1024, 256, 0, stream>>>(w_out, wob, 262144);
    gemm256_qkv<<<384, 512, 0, stream>>>(xn, wqb, qb_, kb_, vb_, theta);
    attn_kernel<<<512, 512, 0, stream>>>(qb_, kb_, vb_, ob_);
    gemm_bt<1><<<512, 256, 0, stream>>>(ob_, wob, nullptr, nullptr, nullptr, x, out, nullptr);
}

// Round 18
// 151.816 us; speedup vs baseline: 1.2130x; 1.2130x over previous
//
#include <hip/hip_runtime.h>
#include <hip/hip_bf16.h>
#include <cstdint>

typedef short short8 __attribute__((ext_vector_type(8)));
typedef float f32x4 __attribute__((ext_vector_type(4)));
typedef unsigned uint4v __attribute__((ext_vector_type(4)));

#define MFMA16(a, b, c) __builtin_amdgcn_mfma_f32_16x16x32_bf16((a), (b), (c), 0, 0, 0)

__device__ __forceinline__ unsigned short f2b(float f) {
    __hip_bfloat16 h = __float2bfloat16(f);
    return __builtin_bit_cast(unsigned short, h);
}

__device__ __forceinline__ void gl_lds16(const void* g, void* l) {
    __builtin_amdgcn_global_load_lds((const __attribute__((address_space(1))) void*)g,
                                     (__attribute__((address_space(3))) void*)l, 16, 0, 0);
}

// (1/8) * log2(e): QK^T scores land in log2 domain -> bare v_exp_f32 softmax
#define QSC 0.18033688011112042f

// ---------------- RMSNorm: fp32 x -> bf16 xn ----------------
__global__ void rmsnorm_kernel(const float* __restrict__ x, const float* __restrict__ scale,
                               unsigned short* __restrict__ xn) {
    const int row = blockIdx.x;
    const int tid = threadIdx.x;
    const float4* xr = (const float4*)(x + (size_t)row * 1024);
    float4 vx = xr[tid];
    float ss = vx.x * vx.x + vx.y * vx.y + vx.z * vx.z + vx.w * vx.w;
#pragma unroll
    for (int m = 1; m < 64; m <<= 1) ss += __shfl_xor(ss, m);
    __shared__ float wsum[4];
    if ((tid & 63) == 0) wsum[tid >> 6] = ss;
    __syncthreads();
    float tot = wsum[0] + wsum[1] + wsum[2] + wsum[3];
    float rs = rsqrtf(tot * (1.0f / 1024.0f) + 1e-6f);
    const float4* sr = (const float4*)scale;
    float4 sv = sr[tid];
    ushort4 r;
    r.x = f2b(vx.x * sv.x * rs);
    r.y = f2b(vx.y * sv.y * rs);
    r.z = f2b(vx.z * sv.z * rs);
    r.w = f2b(vx.w * sv.w * rs);
    *(ushort4*)(xn + (size_t)row * 1024 + tid * 4) = r;
}

// ---------------- f32 -> bf16 convert ----------------
__global__ void f2b_kernel(const float* __restrict__ in, unsigned short* __restrict__ outp, int n4) {
    int i = blockIdx.x * 256 + threadIdx.x;
    if (i < n4) {
        float4 vv = ((const float4*)in)[i];
        ushort4 r;
        r.x = f2b(vv.x);
        r.y = f2b(vv.y);
        r.z = f2b(vv.z);
        r.w = f2b(vv.w);
        ((ushort4*)outp)[i] = r;
    }
}

// ---------------- GEMM C = A * B^T (A: MxK bf16 row-major, B: NxK bf16 row-major) ----
// m97 structure: single-buffered 32 KB LDS, XOR chunk-swizzle (conflict-free ds_read_b128),
// global_load_lds width-16 staging, 2 barriers per K-step, high occupancy.
// EPI 0: scatter qkv; RoPE fused for q,k (q scaled by QSC); v TRANSPOSED (B,H,D,S)
// EPI 1: out[m][n] = acc + skip[m][n]  (fp32)
constexpr int BM = 128, BN = 128, BK = 64, KDIM = 1024, NT = KDIM / BK;

template <int EPI>
__launch_bounds__(256, 4) __global__
    void gemm_bt(const unsigned short* __restrict__ A, const unsigned short* __restrict__ Bw,
                 unsigned short* __restrict__ qo, unsigned short* __restrict__ ko,
                 unsigned short* __restrict__ vo, const float* __restrict__ skip,
                 float* __restrict__ out, const float* __restrict__ theta) {
    __shared__ unsigned short As[BM * BK];
    __shared__ unsigned short Bs[BN * BK];
    const int tid = threadIdx.x;
    const int lane = tid & 63, w = tid >> 6;
    const int wr = w >> 1, wc = w & 1;
    const int lr = lane & 15, lg = lane >> 4;
    // XCD-aware bijective swizzle: each XCD gets 8 consecutive by-rows.
    constexpr int NBX = (EPI == 0) ? 24 : 8;
    const int f = blockIdx.x;
    const int xcd = f & 7, wloc = f >> 3;
    const int g = xcd * (NBX * 8) + wloc;
    const int bx = g % NBX, by = g / NBX;
    const int m0 = by * BM;
    const int n0 = bx * BN;
    const int NCOL = (EPI == 0) ? 3072 : 1024;

    f32x4 acc[4][4] = {};

    // LDS[row][slot] = global[row][chunk slot ^ (row&7)]  (16B chunks, 8 per row)
    auto stage = [&](int kt) {
        const int k0 = kt * BK;
#pragma unroll
        for (int i = 0; i < 4; ++i) {
            int seg = i * 256 + tid;
            int row = seg >> 3, c8 = (seg & 7) ^ (row & 7);
            gl_lds16(A + (size_t)(m0 + row) * KDIM + k0 + c8 * 8, &As[(i * 256 + w * 64) * 8]);
            gl_lds16(Bw + (size_t)(n0 + row) * KDIM + k0 + c8 * 8, &Bs[(i * 256 + w * 64) * 8]);
        }
    };

    for (int kt = 0; kt < NT; ++kt) {
        stage(kt);
        __syncthreads();
#pragma unroll
        for (int kkc = 0; kkc < 2; ++kkc) {
            short8 a[4], b[4];
            const int slot = ((kkc * 4 + lg) ^ (lr & 7)) * 8;
#pragma unroll
            for (int m = 0; m < 4; ++m)
                a[m] = *(const short8*)&As[(wr * 64 + m * 16 + lr) * BK + slot];
#pragma unroll
            for (int n = 0; n < 4; ++n)
                b[n] = *(const short8*)&Bs[(wc * 64 + n * 16 + lr) * BK + slot];
#pragma unroll
            for (int m = 0; m < 4; ++m)
#pragma unroll
                for (int n = 0; n < 4; ++n) acc[m][n] = MFMA16(a[m], b[n], acc[m][n]);
        }
        __syncthreads();
    }

    if (EPI == 0) {
        // whole (block, wc) group is one output tensor c and one head h
        const int colb = n0 + wc * 64;
        const int c = colb >> 10, h = (colb >> 6) & 15;
#pragma unroll
        for (int m = 0; m < 4; ++m) {
            int grow0 = m0 + wr * 64 + m * 16 + lg * 4;
            int b = grow0 >> 10, s0 = grow0 & 1023;
            if (c == 2) {
#pragma unroll
                for (int n = 0; n < 4; ++n) {
                    int d = n * 16 + lr;
                    ushort4 r;
                    r.x = f2b(acc[m][n][0]);
                    r.y = f2b(acc[m][n][1]);
                    r.z = f2b(acc[m][n][2]);
                    r.w = f2b(acc[m][n][3]);
                    *(ushort4*)&vo[(((size_t)(b * 16 + h)) * 64 + d) * 1024 + s0] = r;
                }
            } else {
                unsigned short* dst = (c == 0) ? qo : ko;
                float sc = (c == 0) ? QSC : 1.0f;
#pragma unroll
                for (int j = 0; j < 4; ++j) {
                    int s = s0 + j;
                    float th = theta[((s * 16 + h) << 4) + lr];
                    float sn, cs;
                    __sincosf(th, &sn, &cs);
                    float x1 = acc[m][0][j], x2 = acc[m][1][j];
                    size_t rowb = (((size_t)(b * 16 + h)) * 1024 + s) * 64;
                    dst[rowb + lr]      = f2b((x1 * cs - x2 * sn) * sc);
                    dst[rowb + 16 + lr] = f2b((x2 * cs + x1 * sn) * sc);
                    dst[rowb + 32 + lr] = f2b(acc[m][2][j] * sc);
                    dst[rowb + 48 + lr] = f2b(acc[m][3][j] * sc);
                }
            }
        }
    } else {
#pragma unroll
        for (int m = 0; m < 4; ++m)
#pragma unroll
            for (int n = 0; n < 4; ++n) {
                int gcol = n0 + wc * 64 + n * 16 + lr;
#pragma unroll
                for (int j = 0; j < 4; ++j) {
                    int grow = m0 + wr * 64 + m * 16 + lg * 4 + j;
                    size_t idx = (size_t)grow * NCOL + gcol;
                    out[idx] = acc[m][n][j] + skip[idx];
                }
            }
    }
}

// ---------------- Flash attention (causal), QBLK=256, 8 waves, swapped-operand ------
// q,k: (B,H,S,D) bf16 (q pre-scaled by QSC, rope applied).  vT: (B,H,D,S) bf16.
// o: (B,S,H*D) bf16. Swapped QK^T; in-register softmax (2 shfls); P routed to the
// PV A-fragment via v_permlane32/16_swap in-register transpose (no LDS round-trip,
// no lgkm waits, no bank conflicts). Balanced stripes qmap4; bh->XCD binding.
__launch_bounds__(512, 4) __global__
    void attn_kernel(const unsigned short* __restrict__ q, const unsigned short* __restrict__ k,
                     const unsigned short* __restrict__ vt, unsigned short* __restrict__ o) {
    constexpr int S = 1024, D = 64;
    __shared__ unsigned short Ks[2][64 * 64];  // [t][d], chunk-swizzled
    __shared__ unsigned short Vs[2][64 * 64];  // [d][t], chunk-swizzled
    __shared__ float Lls[8][32];               // per-wave final-l redistribution
    const int tid = threadIdx.x, lane = tid & 63, w = tid >> 6;  // w = 0..7
    const int lr = lane & 15, lg = lane >> 4;
    const int f = blockIdx.x;  // 0..511
    constexpr int qmap4[4] = {3, 2, 0, 1};
    const int qb = qmap4[f >> 7];
    const int bh = (f & 7) * 16 + ((f >> 3) & 15);
    const int qs = qb * 256;
    const size_t base = (size_t)bh * (S * D);
    const int wrow0 = qs + w * 32;

    short8 qf[2][2];
#pragma unroll
    for (int m = 0; m < 2; ++m) {
        const unsigned short* qp = q + base + (size_t)(wrow0 + m * 16 + lr) * D;
        qf[m][0] = *(const short8*)(qp + lg * 8);
        qf[m][1] = *(const short8*)(qp + 32 + lg * 8);
    }

    f32x4 of[2][4] = {};  // O[q = wrow0 + m*16 + lg*4 + j][d = 16*n2 + lr]
    float mrun[2] = {-1e30f, -1e30f};
    float lrun[2] = {0.f, 0.f};  // per-lane partial (own t-subset); reduced at end

    const int nkt = 4 * qb + 4;

    // one 16B chunk per thread per tensor: 512 threads x 16B = one 64x64 bf16 tile
    const int srow = tid >> 3, sc8 = (tid & 7) ^ (srow & 7);
    auto stageK = [&](int buf, int kt) {
        gl_lds16(k + base + (size_t)(kt * 64 + srow) * D + sc8 * 8, &Ks[buf][w * 512]);
    };
    auto stageV = [&](int buf, int kt) {
        gl_lds16(vt + base + (size_t)srow * S + kt * 64 + sc8 * 8, &Vs[buf][w * 512]);
    };

    stageK(0, 0);
    stageV(0, 0);
    __syncthreads();

    for (int kt = 0; kt < nkt; ++kt) {
        const int b = kt & 1;
        if (kt + 1 < nkt) {
            stageK(b ^ 1, kt + 1);
            stageV(b ^ 1, kt + 1);
        }

        if (kt * 64 <= wrow0 + 31) {  // wave-uniform: this wave has unmasked rows
            // Swapped QK^T: sf[m][n][j] = S^T[t = kt*64+16n+lg*4+j][q = wrow0+m*16+lr]
            f32x4 sf[2][4] = {};
            __builtin_amdgcn_s_setprio(1);
#pragma unroll
            for (int n = 0; n < 4; ++n) {
                const int r = n * 16 + lr;
#pragma unroll
                for (int kkc = 0; kkc < 2; ++kkc) {
                    short8 kf = *(const short8*)&Ks[b][r * 64 + (((kkc * 4 + lg) ^ (lr & 7)) * 8)];
#pragma unroll
                    for (int m = 0; m < 2; ++m) sf[m][n] = MFMA16(kf, qf[m][kkc], sf[m][n]);
                }
            }
            __builtin_amdgcn_s_setprio(0);

            if (kt * 64 + 63 > wrow0) {  // tile overlaps diagonal for this wave
#pragma unroll
                for (int m = 0; m < 2; ++m)
#pragma unroll
                    for (int n = 0; n < 4; ++n)
#pragma unroll
                        for (int j = 0; j < 4; ++j) {
                            int t = kt * 64 + 16 * n + lg * 4 + j;
                            int qr = wrow0 + m * 16 + lr;
                            if (t > qr) sf[m][n][j] = -1e30f;
                        }
            }

#pragma unroll
            for (int m = 0; m < 2; ++m) {
                float mx = -1e30f;
#pragma unroll
                for (int n = 0; n < 4; ++n)
                    mx = fmaxf(mx, fmaxf(fmaxf(sf[m][n][0], sf[m][n][1]),
                                         fmaxf(sf[m][n][2], sf[m][n][3])));
                mx = fmaxf(mx, __shfl_xor(mx, 16));
                mx = fmaxf(mx, __shfl_xor(mx, 32));

                if (__any(mx > mrun[m] + 8.0f)) {
                    float newm = fmaxf(mrun[m], mx);
                    float sc = __builtin_amdgcn_exp2f(mrun[m] - newm);
                    mrun[m] = newm;
                    float psum = 0.f;
#pragma unroll
                    for (int n = 0; n < 4; ++n)
#pragma unroll
                        for (int j = 0; j < 4; ++j) {
                            float p = __builtin_amdgcn_exp2f(sf[m][n][j] - newm);
                            sf[m][n][j] = p;
                            psum += p;
                        }
                    lrun[m] = lrun[m] * sc + psum;
#pragma unroll
                    for (int n2 = 0; n2 < 4; ++n2) of[m][n2] *= sc;
                } else {
                    float mo = mrun[m];
                    float psum = 0.f;
#pragma unroll
                    for (int n = 0; n < 4; ++n)
#pragma unroll
                        for (int j = 0; j < 4; ++j) {
                            float p = __builtin_amdgcn_exp2f(sf[m][n][j] - mo);
                            sf[m][n][j] = p;
                            psum += p;
                        }
                    lrun[m] += psum;
                }
            }

            // P -> PV A-frags via permlane32/16_swap in-register transpose (no LDS).
            // Source dword Dk[n][w2] holds t-pair tp = 8n + 2lg + w2 (lo = even t), q = lr.
            // tp bits: [0]=w2 [1]=lane-b4 [2]=lane-b5 [3]=n0 [4]=n1.
            // Target A-frag: lane-b4=tp2, lane-b5=tp3, dword dd=(tp1,tp0), kkc=tp4.
            short8 pa[2][2];  // [m][kkc]
#pragma unroll
            for (int m = 0; m < 2; ++m) {
                unsigned Dk[4][2];
#pragma unroll
                for (int n = 0; n < 4; ++n)
#pragma unroll
                    for (int w2 = 0; w2 < 2; ++w2)
                        Dk[n][w2] = (unsigned)f2b(sf[m][n][2 * w2]) |
                                    ((unsigned)f2b(sf[m][n][2 * w2 + 1]) << 16);
#pragma unroll
                for (int n1 = 0; n1 < 2; ++n1) {
                    unsigned fr[4];
#pragma unroll
                    for (int w2 = 0; w2 < 2; ++w2) {
                        unsigned X0 = Dk[2 * n1][w2];      // r=0 (n0=0)
                        unsigned X1 = Dk[2 * n1 + 1][w2];  // r=1 (n0=1)
                        asm("v_permlane32_swap_b32 %0, %1" : "+v"(X0), "+v"(X1));
                        asm("v_permlane16_swap_b32 %0, %1" : "+v"(X0), "+v"(X1));
                        fr[w2] = X0;      // dd = w2
                        fr[2 + w2] = X1;  // dd = 2 + w2
                    }
                    uint4v t4 = {fr[0], fr[1], fr[2], fr[3]};
                    pa[m][n1] = __builtin_bit_cast(short8, t4);
                }
            }

            // PV: O[q][d] += P[q][t] * V[t][d]; V^T-frag read identical to K-frag
            __builtin_amdgcn_s_setprio(1);
#pragma unroll
            for (int kkc = 0; kkc < 2; ++kkc) {
#pragma unroll
                for (int n2 = 0; n2 < 4; ++n2) {
                    const int r = n2 * 16 + lr;
                    short8 bv = *(const short8*)&Vs[b][r * 64 + (((kkc * 4 + lg) ^ (lr & 7)) * 8)];
#pragma unroll
                    for (int m = 0; m < 2; ++m) of[m][n2] = MFMA16(pa[m][kkc], bv, of[m][n2]);
                }
            }
            __builtin_amdgcn_s_setprio(0);
        }

        __syncthreads();
    }

    // final l per q-row, redistributed through the per-wave L buffer
#pragma unroll
    for (int m = 0; m < 2; ++m) {
        float l = lrun[m];
        l += __shfl_xor(l, 16);
        l += __shfl_xor(l, 32);
        Lls[w][m * 16 + lr] = l;  // all lg write the same value
    }
    const int bb = bh >> 4, h = bh & 15;
#pragma unroll
    for (int m = 0; m < 2; ++m)
#pragma unroll
        for (int j = 0; j < 4; ++j) {
            float inv = 1.f / Lls[w][m * 16 + lg * 4 + j];
            int orow = wrow0 + m * 16 + lg * 4 + j;
            size_t ob = ((size_t)(bb * 1024 + orow)) * 1024 + h * 64;
#pragma unroll
            for (int n2 = 0; n2 < 4; ++n2)
                o[ob + n2 * 16 + lr] = f2b(of[m][n2][j] * inv);
        }
}

extern "C" void kernel_launch(void* const* d_in, const int* in_sizes, int n_in, void* d_out,
                              int out_size, void* d_ws, size_t ws_size, hipStream_t stream) {
    const float* x = (const float*)d_in[0];
    const float* scale = (const float*)d_in[1];
    const float* w_qkv = (const float*)d_in[2];
    const float* w_out = (const float*)d_in[3];
    const float* theta = (const float*)d_in[4];
    float* out = (float*)d_out;

    char* p = (char*)d_ws;
    unsigned short* xn = (unsigned short*)p;      p += (size_t)8192 * 1024 * 2;
    unsigned short* wqb = (unsigned short*)p;     p += (size_t)3072 * 1024 * 2;
    unsigned short* wob = (unsigned short*)p;     p += (size_t)1024 * 1024 * 2;
    unsigned short* qb_ = (unsigned short*)p;     p += (size_t)128 * 1024 * 64 * 2;
    unsigned short* kb_ = (unsigned short*)p;     p += (size_t)128 * 1024 * 64 * 2;
    unsigned short* vb_ = (unsigned short*)p;     p += (size_t)128 * 1024 * 64 * 2;  // V^T (B,H,D,S)
    unsigned short* ob_ = (unsigned short*)p;     p += (size_t)8192 * 1024 * 2;

    rmsnorm_kernel<<<8192, 256, 0, stream>>>(x, scale, xn);
    f2b_kernel<<<3072, 256, 0, stream>>>(w_qkv, wqb, 786432);
    f2b_kernel<<<1024, 256, 0, stream>>>(w_out, wob, 262144);
    gemm_bt<0><<<1536, 256, 0, stream>>>(xn, wqb, qb_, kb_, vb_, nullptr, nullptr, theta);
    attn_kernel<<<512, 512, 0, stream>>>(qb_, kb_, vb_, ob_);
    gemm_bt<1><<<512, 256, 0, stream>>>(ob_, wob, nullptr, nullptr, nullptr, x, out, nullptr);
}

// Round 19
// 148.610 us; speedup vs baseline: 1.2392x; 1.0216x over previous
//
#include <hip/hip_runtime.h>
#include <hip/hip_bf16.h>
#include <cstdint>

typedef short short8 __attribute__((ext_vector_type(8)));
typedef float f32x4 __attribute__((ext_vector_type(4)));
typedef unsigned uint4v __attribute__((ext_vector_type(4)));

#define MFMA16(a, b, c) __builtin_amdgcn_mfma_f32_16x16x32_bf16((a), (b), (c), 0, 0, 0)

__device__ __forceinline__ unsigned short f2b(float f) {
    __hip_bfloat16 h = __float2bfloat16(f);
    return __builtin_bit_cast(unsigned short, h);
}

__device__ __forceinline__ void gl_lds16(const void* g, void* l) {
    __builtin_amdgcn_global_load_lds((const __attribute__((address_space(1))) void*)g,
                                     (__attribute__((address_space(3))) void*)l, 16, 0, 0);
}

// (1/8) * log2(e): QK^T scores land in log2 domain -> bare v_exp_f32 softmax
#define QSC 0.18033688011112042f

// ---------------- Fused prep: RMSNorm (x -> bf16 xn) + f32->bf16 weight converts ----
// blocks 0..8191: rmsnorm row; 8192..11263: w_qkv chunks; 11264..12287: w_out chunks.
__global__ void prep_kernel(const float* __restrict__ x, const float* __restrict__ scale,
                            unsigned short* __restrict__ xn, const float* __restrict__ w_qkv,
                            unsigned short* __restrict__ wqb, const float* __restrict__ w_out,
                            unsigned short* __restrict__ wob) {
    const int bid = blockIdx.x;
    const int tid = threadIdx.x;
    if (bid < 8192) {
        const int row = bid;
        const float4* xr = (const float4*)(x + (size_t)row * 1024);
        float4 vx = xr[tid];
        float ss = vx.x * vx.x + vx.y * vx.y + vx.z * vx.z + vx.w * vx.w;
#pragma unroll
        for (int m = 1; m < 64; m <<= 1) ss += __shfl_xor(ss, m);
        __shared__ float wsum[4];
        if ((tid & 63) == 0) wsum[tid >> 6] = ss;
        __syncthreads();
        float tot = wsum[0] + wsum[1] + wsum[2] + wsum[3];
        float rs = rsqrtf(tot * (1.0f / 1024.0f) + 1e-6f);
        const float4* sr = (const float4*)scale;
        float4 sv = sr[tid];
        ushort4 r;
        r.x = f2b(vx.x * sv.x * rs);
        r.y = f2b(vx.y * sv.y * rs);
        r.z = f2b(vx.z * sv.z * rs);
        r.w = f2b(vx.w * sv.w * rs);
        *(ushort4*)(xn + (size_t)row * 1024 + tid * 4) = r;
    } else {
        const float* in;
        unsigned short* outp;
        int i;
        if (bid < 11264) {
            in = w_qkv;
            outp = wqb;
            i = (bid - 8192) * 256 + tid;  // < 786432 always
        } else {
            in = w_out;
            outp = wob;
            i = (bid - 11264) * 256 + tid;  // < 262144 always
        }
        float4 vv = ((const float4*)in)[i];
        ushort4 r;
        r.x = f2b(vv.x);
        r.y = f2b(vv.y);
        r.z = f2b(vv.z);
        r.w = f2b(vv.w);
        ((ushort4*)outp)[i] = r;
    }
}

// ---------------- GEMM C = A * B^T (A: MxK bf16 row-major, B: NxK bf16 row-major) ----
// m97 structure: single-buffered 32 KB LDS, XOR chunk-swizzle (conflict-free ds_read_b128),
// global_load_lds width-16 staging, 2 barriers per K-step, high occupancy.
// EPI 0: scatter qkv; RoPE fused for q,k (q scaled by QSC); v TRANSPOSED (B,H,D,S)
// EPI 1: out[m][n] = acc + skip[m][n]  (fp32)
constexpr int BM = 128, BN = 128, BK = 64, KDIM = 1024, NT = KDIM / BK;

template <int EPI>
__launch_bounds__(256, 4) __global__
    void gemm_bt(const unsigned short* __restrict__ A, const unsigned short* __restrict__ Bw,
                 unsigned short* __restrict__ qo, unsigned short* __restrict__ ko,
                 unsigned short* __restrict__ vo, const float* __restrict__ skip,
                 float* __restrict__ out, const float* __restrict__ theta) {
    __shared__ unsigned short As[BM * BK];
    __shared__ unsigned short Bs[BN * BK];
    const int tid = threadIdx.x;
    const int lane = tid & 63, w = tid >> 6;
    const int wr = w >> 1, wc = w & 1;
    const int lr = lane & 15, lg = lane >> 4;
    // XCD-aware bijective swizzle: each XCD gets 8 consecutive by-rows.
    constexpr int NBX = (EPI == 0) ? 24 : 8;
    const int f = blockIdx.x;
    const int xcd = f & 7, wloc = f >> 3;
    const int g = xcd * (NBX * 8) + wloc;
    const int bx = g % NBX, by = g / NBX;
    const int m0 = by * BM;
    const int n0 = bx * BN;
    const int NCOL = (EPI == 0) ? 3072 : 1024;

    f32x4 acc[4][4] = {};

    // LDS[row][slot] = global[row][chunk slot ^ (row&7)]  (16B chunks, 8 per row)
    auto stage = [&](int kt) {
        const int k0 = kt * BK;
#pragma unroll
        for (int i = 0; i < 4; ++i) {
            int seg = i * 256 + tid;
            int row = seg >> 3, c8 = (seg & 7) ^ (row & 7);
            gl_lds16(A + (size_t)(m0 + row) * KDIM + k0 + c8 * 8, &As[(i * 256 + w * 64) * 8]);
            gl_lds16(Bw + (size_t)(n0 + row) * KDIM + k0 + c8 * 8, &Bs[(i * 256 + w * 64) * 8]);
        }
    };

    for (int kt = 0; kt < NT; ++kt) {
        stage(kt);
        __syncthreads();
#pragma unroll
        for (int kkc = 0; kkc < 2; ++kkc) {
            short8 a[4], b[4];
            const int slot = ((kkc * 4 + lg) ^ (lr & 7)) * 8;
#pragma unroll
            for (int m = 0; m < 4; ++m)
                a[m] = *(const short8*)&As[(wr * 64 + m * 16 + lr) * BK + slot];
#pragma unroll
            for (int n = 0; n < 4; ++n)
                b[n] = *(const short8*)&Bs[(wc * 64 + n * 16 + lr) * BK + slot];
#pragma unroll
            for (int m = 0; m < 4; ++m)
#pragma unroll
                for (int n = 0; n < 4; ++n) acc[m][n] = MFMA16(a[m], b[n], acc[m][n]);
        }
        __syncthreads();
    }

    if (EPI == 0) {
        // whole (block, wc) group is one output tensor c and one head h
        const int colb = n0 + wc * 64;
        const int c = colb >> 10, h = (colb >> 6) & 15;
#pragma unroll
        for (int m = 0; m < 4; ++m) {
            int grow0 = m0 + wr * 64 + m * 16 + lg * 4;
            int b = grow0 >> 10, s0 = grow0 & 1023;
            if (c == 2) {
#pragma unroll
                for (int n = 0; n < 4; ++n) {
                    int d = n * 16 + lr;
                    ushort4 r;
                    r.x = f2b(acc[m][n][0]);
                    r.y = f2b(acc[m][n][1]);
                    r.z = f2b(acc[m][n][2]);
                    r.w = f2b(acc[m][n][3]);
                    *(ushort4*)&vo[(((size_t)(b * 16 + h)) * 64 + d) * 1024 + s0] = r;
                }
            } else {
                unsigned short* dst = (c == 0) ? qo : ko;
                float sc = (c == 0) ? QSC : 1.0f;
#pragma unroll
                for (int j = 0; j < 4; ++j) {
                    int s = s0 + j;
                    float th = theta[((s * 16 + h) << 4) + lr];
                    float sn, cs;
                    __sincosf(th, &sn, &cs);
                    float x1 = acc[m][0][j], x2 = acc[m][1][j];
                    size_t rowb = (((size_t)(b * 16 + h)) * 1024 + s) * 64;
                    dst[rowb + lr]      = f2b((x1 * cs - x2 * sn) * sc);
                    dst[rowb + 16 + lr] = f2b((x2 * cs + x1 * sn) * sc);
                    dst[rowb + 32 + lr] = f2b(acc[m][2][j] * sc);
                    dst[rowb + 48 + lr] = f2b(acc[m][3][j] * sc);
                }
            }
        }
    } else {
#pragma unroll
        for (int m = 0; m < 4; ++m)
#pragma unroll
            for (int n = 0; n < 4; ++n) {
                int gcol = n0 + wc * 64 + n * 16 + lr;
#pragma unroll
                for (int j = 0; j < 4; ++j) {
                    int grow = m0 + wr * 64 + m * 16 + lg * 4 + j;
                    size_t idx = (size_t)grow * NCOL + gcol;
                    out[idx] = acc[m][n][j] + skip[idx];
                }
            }
    }
}

// ---------------- Flash attention (causal), QBLK=256, 8 waves, swapped-operand ------
// q,k: (B,H,S,D) bf16 (q pre-scaled by QSC, rope applied).  vT: (B,H,D,S) bf16.
// o: (B,S,H*D) bf16. Swapped QK^T; in-register softmax (2 shfls); P routed to the
// PV A-fragment via v_permlane32/16_swap in-register transpose (no LDS round-trip,
// no lgkm waits, no bank conflicts). Balanced stripes qmap4; bh->XCD binding.
__launch_bounds__(512, 4) __global__
    void attn_kernel(const unsigned short* __restrict__ q, const unsigned short* __restrict__ k,
                     const unsigned short* __restrict__ vt, unsigned short* __restrict__ o) {
    constexpr int S = 1024, D = 64;
    __shared__ unsigned short Ks[2][64 * 64];  // [t][d], chunk-swizzled
    __shared__ unsigned short Vs[2][64 * 64];  // [d][t], chunk-swizzled
    __shared__ float Lls[8][32];               // per-wave final-l redistribution
    const int tid = threadIdx.x, lane = tid & 63, w = tid >> 6;  // w = 0..7
    const int lr = lane & 15, lg = lane >> 4;
    const int f = blockIdx.x;  // 0..511
    constexpr int qmap4[4] = {3, 2, 0, 1};
    const int qb = qmap4[f >> 7];
    const int bh = (f & 7) * 16 + ((f >> 3) & 15);
    const int qs = qb * 256;
    const size_t base = (size_t)bh * (S * D);
    const int wrow0 = qs + w * 32;

    short8 qf[2][2];
#pragma unroll
    for (int m = 0; m < 2; ++m) {
        const unsigned short* qp = q + base + (size_t)(wrow0 + m * 16 + lr) * D;
        qf[m][0] = *(const short8*)(qp + lg * 8);
        qf[m][1] = *(const short8*)(qp + 32 + lg * 8);
    }

    f32x4 of[2][4] = {};  // O[q = wrow0 + m*16 + lg*4 + j][d = 16*n2 + lr]
    float mrun[2] = {-1e30f, -1e30f};
    float lrun[2] = {0.f, 0.f};  // per-lane partial (own t-subset); reduced at end

    const int nkt = 4 * qb + 4;

    // one 16B chunk per thread per tensor: 512 threads x 16B = one 64x64 bf16 tile
    const int srow = tid >> 3, sc8 = (tid & 7) ^ (srow & 7);
    auto stageK = [&](int buf, int kt) {
        gl_lds16(k + base + (size_t)(kt * 64 + srow) * D + sc8 * 8, &Ks[buf][w * 512]);
    };
    auto stageV = [&](int buf, int kt) {
        gl_lds16(vt + base + (size_t)srow * S + kt * 64 + sc8 * 8, &Vs[buf][w * 512]);
    };

    stageK(0, 0);
    stageV(0, 0);
    __syncthreads();

    for (int kt = 0; kt < nkt; ++kt) {
        const int b = kt & 1;
        if (kt + 1 < nkt) {
            stageK(b ^ 1, kt + 1);
            stageV(b ^ 1, kt + 1);
        }

        if (kt * 64 <= wrow0 + 31) {  // wave-uniform: this wave has unmasked rows
            // Swapped QK^T: sf[m][n][j] = S^T[t = kt*64+16n+lg*4+j][q = wrow0+m*16+lr]
            f32x4 sf[2][4] = {};
            __builtin_amdgcn_s_setprio(1);
#pragma unroll
            for (int n = 0; n < 4; ++n) {
                const int r = n * 16 + lr;
#pragma unroll
                for (int kkc = 0; kkc < 2; ++kkc) {
                    short8 kf = *(const short8*)&Ks[b][r * 64 + (((kkc * 4 + lg) ^ (lr & 7)) * 8)];
#pragma unroll
                    for (int m = 0; m < 2; ++m) sf[m][n] = MFMA16(kf, qf[m][kkc], sf[m][n]);
                }
            }
            __builtin_amdgcn_s_setprio(0);

            if (kt * 64 + 63 > wrow0) {  // tile overlaps diagonal for this wave
#pragma unroll
                for (int m = 0; m < 2; ++m)
#pragma unroll
                    for (int n = 0; n < 4; ++n)
#pragma unroll
                        for (int j = 0; j < 4; ++j) {
                            int t = kt * 64 + 16 * n + lg * 4 + j;
                            int qr = wrow0 + m * 16 + lr;
                            if (t > qr) sf[m][n][j] = -1e30f;
                        }
            }

#pragma unroll
            for (int m = 0; m < 2; ++m) {
                float mx = -1e30f;
#pragma unroll
                for (int n = 0; n < 4; ++n)
                    mx = fmaxf(mx, fmaxf(fmaxf(sf[m][n][0], sf[m][n][1]),
                                         fmaxf(sf[m][n][2], sf[m][n][3])));
                mx = fmaxf(mx, __shfl_xor(mx, 16));
                mx = fmaxf(mx, __shfl_xor(mx, 32));

                if (__any(mx > mrun[m] + 8.0f)) {
                    float newm = fmaxf(mrun[m], mx);
                    float sc = __builtin_amdgcn_exp2f(mrun[m] - newm);
                    mrun[m] = newm;
                    float psum = 0.f;
#pragma unroll
                    for (int n = 0; n < 4; ++n)
#pragma unroll
                        for (int j = 0; j < 4; ++j) {
                            float p = __builtin_amdgcn_exp2f(sf[m][n][j] - newm);
                            sf[m][n][j] = p;
                            psum += p;
                        }
                    lrun[m] = lrun[m] * sc + psum;
#pragma unroll
                    for (int n2 = 0; n2 < 4; ++n2) of[m][n2] *= sc;
                } else {
                    float mo = mrun[m];
                    float psum = 0.f;
#pragma unroll
                    for (int n = 0; n < 4; ++n)
#pragma unroll
                        for (int j = 0; j < 4; ++j) {
                            float p = __builtin_amdgcn_exp2f(sf[m][n][j] - mo);
                            sf[m][n][j] = p;
                            psum += p;
                        }
                    lrun[m] += psum;
                }
            }

            // P -> PV A-frags via permlane32/16_swap in-register transpose (no LDS).
            // Source dword Dk[n][w2] holds t-pair tp = 8n + 2lg + w2 (lo = even t), q = lr.
            // tp bits: [0]=w2 [1]=lane-b4 [2]=lane-b5 [3]=n0 [4]=n1.
            // Target A-frag: lane-b4=tp2, lane-b5=tp3, dword dd=(tp1,tp0), kkc=tp4.
            short8 pa[2][2];  // [m][kkc]
#pragma unroll
            for (int m = 0; m < 2; ++m) {
                unsigned Dk[4][2];
#pragma unroll
                for (int n = 0; n < 4; ++n)
#pragma unroll
                    for (int w2 = 0; w2 < 2; ++w2)
                        Dk[n][w2] = (unsigned)f2b(sf[m][n][2 * w2]) |
                                    ((unsigned)f2b(sf[m][n][2 * w2 + 1]) << 16);
#pragma unroll
                for (int n1 = 0; n1 < 2; ++n1) {
                    unsigned fr[4];
#pragma unroll
                    for (int w2 = 0; w2 < 2; ++w2) {
                        unsigned X0 = Dk[2 * n1][w2];      // r=0 (n0=0)
                        unsigned X1 = Dk[2 * n1 + 1][w2];  // r=1 (n0=1)
                        asm("v_permlane32_swap_b32 %0, %1" : "+v"(X0), "+v"(X1));
                        asm("v_permlane16_swap_b32 %0, %1" : "+v"(X0), "+v"(X1));
                        fr[w2] = X0;      // dd = w2
                        fr[2 + w2] = X1;  // dd = 2 + w2
                    }
                    uint4v t4 = {fr[0], fr[1], fr[2], fr[3]};
                    pa[m][n1] = __builtin_bit_cast(short8, t4);
                }
            }

            // PV: O[q][d] += P[q][t] * V[t][d]; V^T-frag read identical to K-frag
            __builtin_amdgcn_s_setprio(1);
#pragma unroll
            for (int kkc = 0; kkc < 2; ++kkc) {
#pragma unroll
                for (int n2 = 0; n2 < 4; ++n2) {
                    const int r = n2 * 16 + lr;
                    short8 bv = *(const short8*)&Vs[b][r * 64 + (((kkc * 4 + lg) ^ (lr & 7)) * 8)];
#pragma unroll
                    for (int m = 0; m < 2; ++m) of[m][n2] = MFMA16(pa[m][kkc], bv, of[m][n2]);
                }
            }
            __builtin_amdgcn_s_setprio(0);
        }

        __syncthreads();
    }

    // final l per q-row, redistributed through the per-wave L buffer
#pragma unroll
    for (int m = 0; m < 2; ++m) {
        float l = lrun[m];
        l += __shfl_xor(l, 16);
        l += __shfl_xor(l, 32);
        Lls[w][m * 16 + lr] = l;  // all lg write the same value
    }
    const int bb = bh >> 4, h = bh & 15;
#pragma unroll
    for (int m = 0; m < 2; ++m)
#pragma unroll
        for (int j = 0; j < 4; ++j) {
            float inv = 1.f / Lls[w][m * 16 + lg * 4 + j];
            int orow = wrow0 + m * 16 + lg * 4 + j;
            size_t ob = ((size_t)(bb * 1024 + orow)) * 1024 + h * 64;
#pragma unroll
            for (int n2 = 0; n2 < 4; ++n2)
                o[ob + n2 * 16 + lr] = f2b(of[m][n2][j] * inv);
        }
}

extern "C" void kernel_launch(void* const* d_in, const int* in_sizes, int n_in, void* d_out,
                              int out_size, void* d_ws, size_t ws_size, hipStream_t stream) {
    const float* x = (const float*)d_in[0];
    const float* scale = (const float*)d_in[1];
    const float* w_qkv = (const float*)d_in[2];
    const float* w_out = (const float*)d_in[3];
    const float* theta = (const float*)d_in[4];
    float* out = (float*)d_out;

    char* p = (char*)d_ws;
    unsigned short* xn = (unsigned short*)p;      p += (size_t)8192 * 1024 * 2;
    unsigned short* wqb = (unsigned short*)p;     p += (size_t)3072 * 1024 * 2;
    unsigned short* wob = (unsigned short*)p;     p += (size_t)1024 * 1024 * 2;
    unsigned short* qb_ = (unsigned short*)p;     p += (size_t)128 * 1024 * 64 * 2;
    unsigned short* kb_ = (unsigned short*)p;     p += (size_t)128 * 1024 * 64 * 2;
    unsigned short* vb_ = (unsigned short*)p;     p += (size_t)128 * 1024 * 64 * 2;  // V^T (B,H,D,S)
    unsigned short* ob_ = (unsigned short*)p;     p += (size_t)8192 * 1024 * 2;

    prep_kernel<<<12288, 256, 0, stream>>>(x, scale, xn, w_qkv, wqb, w_out, wob);
    gemm_bt<0><<<1536, 256, 0, stream>>>(xn, wqb, qb_, kb_, vb_, nullptr, nullptr, theta);
    attn_kernel<<<512, 512, 0, stream>>>(qb_, kb_, vb_, ob_);
    gemm_bt<1><<<512, 256, 0, stream>>>(ob_, wob, nullptr, nullptr, nullptr, x, out, nullptr);
}